// Round 7
// baseline (985.790 us; speedup 1.0000x reference)
//
#include <hip/hip_runtime.h>
#include <hip/hip_bf16.h>
#include <math.h>

#define IGNORE_INDEX (-100)

static constexpr int Dc = 1024, Vc = 128000;
static constexpr int Mrows = 2048;        // B*S
static constexpr int Kdim = Dc;           // 1024
static constexpr int NT = Kdim / 64;      // 16 K-tiles of BK=64
static constexpr int NCHUNK = Vc / 64;    // 2000 partial chunks per row

typedef __bf16 bf16x8_t __attribute__((ext_vector_type(8)));
typedef float f32x4_t __attribute__((ext_vector_type(4)));

__device__ __forceinline__ ushort f2bf(float f) {
  union { float f; unsigned u; } v; v.f = f;
  unsigned u = v.u;
  unsigned r = (u + 0x7FFFu + ((u >> 16) & 1u)) >> 16;  // round-nearest-even
  return (ushort)r;
}

// ---------------- cast fp32 -> bf16 (vectorized, grid-stride) ----------------
__global__ void cast_f32_bf16(const float* __restrict__ in, ushort* __restrict__ out,
                              size_t n4) {
  size_t i = (size_t)blockIdx.x * blockDim.x + threadIdx.x;
  size_t stride = (size_t)gridDim.x * blockDim.x;
  for (; i < n4; i += stride) {
    float4 v = reinterpret_cast<const float4*>(in)[i];
    ushort4 o;
    o.x = f2bf(v.x); o.y = f2bf(v.y); o.z = f2bf(v.z); o.w = f2bf(v.w);
    reinterpret_cast<ushort4*>(out)[i] = o;
  }
}

// ---------------- target logits: fp32 dot(hidden[r], weight[t[r]]) ----------------
__global__ void tgt_kernel(const float* __restrict__ hidden, const float* __restrict__ weight,
                           const int* __restrict__ targets, float* __restrict__ tgt) {
  int row = blockIdx.x * 4 + (threadIdx.x >> 6);
  int lane = threadIdx.x & 63;
  if (row >= Mrows) return;
  int t = targets[row];
  float sum = 0.f;
  if (t != IGNORE_INDEX) {
    const float* h = hidden + (size_t)row * Kdim;
    const float* wv = weight + (size_t)t * Kdim;
    for (int k = lane * 4; k < Kdim; k += 64 * 4) {
      float4 a = *reinterpret_cast<const float4*>(h + k);
      float4 b = *reinterpret_cast<const float4*>(wv + k);
      sum += a.x * b.x + a.y * b.y + a.z * b.z + a.w * b.w;
    }
  }
  #pragma unroll
  for (int d = 1; d < 64; d <<= 1) sum += __shfl_xor(sum, d);
  if (lane == 0) tgt[row] = sum;
}

// ---------------- 256x256 4-wave GEMM (bf16 MFMA) + fused partial LSE ----------
// Waves 2x2, per-wave C = 128x128 (8x8 frags of 16x16x32, acc = 256 VGPRs).
// LDS: 2 dbuf x {A,B}, each [256 rows][64 k] bf16 = 32KB -> 128KB total.
// DS-read bytes/tile = (2+2)x32KB = 128KB (vs 192KB for the 2x4 grid).
// Swizzle: 16B slot s' = s ^ (row&7) within each 128B row (involution); applied
// as linear LDS dest + inverse-swizzled GLOBAL source + swizzled ds_read (rule #21).
// ONE barrier + ONE vmcnt(0) per K-tile: stages for t+1 issued at tile top into
// buf^1 (whose previous readers all passed the prior barrier), drained at tile end.
__device__ __forceinline__ void stage_tile(ushort* Ar, ushort* Br,
                                           const ushort* gA, const ushort* gB,
                                           int k0, int wid, int lane) {
  #pragma unroll
  for (int j = 0; j < 8; ++j) {
    int c = wid * 512 + j * 64 + lane;   // 16B chunk id, 0..2047 (8 chunks/128B row)
    int r = c >> 3, slot = c & 7;
    int ko = ((slot ^ (r & 7)) << 3);    // inverse-swizzled source k-offset (elements)
    const ushort* ga = gA + (size_t)r * Kdim + k0 + ko;
    const ushort* gb = gB + (size_t)r * Kdim + k0 + ko;
    __builtin_amdgcn_global_load_lds(
        (const __attribute__((address_space(1))) void*)ga,
        (__attribute__((address_space(3))) void*)(Ar + c * 8), 16, 0, 0);
    __builtin_amdgcn_global_load_lds(
        (const __attribute__((address_space(1))) void*)gb,
        (__attribute__((address_space(3))) void*)(Br + c * 8), 16, 0, 0);
  }
}

#define MFMA_BF16(A, B, C) __builtin_amdgcn_mfma_f32_16x16x32_bf16((A), (B), (C), 0, 0, 0)

__global__ __launch_bounds__(256, 1) void gemm_lse4(const ushort* __restrict__ Abf,
                                                    const ushort* __restrict__ Bbf,
                                                    float2* __restrict__ part) {
  __shared__ ushort lds[2][2][16384];   // [dbuf][A,B][256*64] = 128KB
  const int tid = threadIdx.x;
  const int wid = tid >> 6, lane = tid & 63;
  const int wr = wid >> 1, wc = wid & 1;        // 2M x 2N wave grid
  const int l15 = lane & 15, l16 = lane >> 4;
  const int bid = blockIdx.x;
  const int mb = bid & 7;              // bid%8 = XCD -> each XCD owns one A panel
  const int nb = bid >> 3;             // 0..499; all XCDs stream same B panel together

  // swizzled read offset: slot = ks*4 + l16, row&7 = l15&7
  const int swz = l15 & 7;
  const int koff0 = ((l16 ^ swz) << 4);            // bytes; ks=1 -> koff0 ^ 64
  const int aBase = (wr * 128 + l15) * 128;        // bytes; + mi*2048 per frag
  const int bBase = (wc * 128 + l15) * 128;        // bytes; + ni*2048 per frag

  const ushort* gA = Abf + (size_t)(mb * 256) * Kdim;
  const ushort* gB = Bbf + (size_t)(nb * 256) * Kdim;

  f32x4_t acc[8][8];
  #pragma unroll
  for (int i = 0; i < 8; ++i)
    #pragma unroll
    for (int j = 0; j < 8; ++j)
      acc[i][j] = (f32x4_t){0.f, 0.f, 0.f, 0.f};

  // prologue: stage tile 0
  stage_tile(lds[0][0], lds[0][1], gA, gB, 0, wid, lane);
  asm volatile("s_waitcnt vmcnt(0)" ::: "memory");
  __builtin_amdgcn_s_barrier();

  for (int t = 0; t < NT; ++t) {
    const int buf = t & 1;
    if (t + 1 < NT)
      stage_tile(lds[buf ^ 1][0], lds[buf ^ 1][1], gA, gB, (t + 1) * 64, wid, lane);

    #pragma unroll
    for (int ks = 0; ks < 2; ++ks) {
      const int koff = koff0 ^ (ks << 6);
      bf16x8_t a[8], b[8];
      #pragma unroll
      for (int mi = 0; mi < 8; ++mi)
        a[mi] = *reinterpret_cast<const bf16x8_t*>(
            (const char*)lds[buf][0] + aBase + mi * 2048 + koff);
      #pragma unroll
      for (int ni = 0; ni < 8; ++ni)
        b[ni] = *reinterpret_cast<const bf16x8_t*>(
            (const char*)lds[buf][1] + bBase + ni * 2048 + koff);
      __builtin_amdgcn_s_setprio(1);
      #pragma unroll
      for (int mi = 0; mi < 8; ++mi)
        #pragma unroll
        for (int ni = 0; ni < 8; ++ni)
          acc[mi][ni] = MFMA_BF16(a[mi], b[ni], acc[mi][ni]);
      __builtin_amdgcn_s_setprio(0);
    }

    asm volatile("s_waitcnt vmcnt(0)" ::: "memory");
    __builtin_amdgcn_s_barrier();
  }

  // fused partial-LSE epilogue. acc[mi][ni][j]: row = wr*128+mi*16+l16*4+j,
  // col = wc*128+ni*16+l15 (m89-verified C/D layout). Two 64-col chunks (h).
  const int chunk0 = nb * 4 + wc * 2;
  #pragma unroll
  for (int mi = 0; mi < 8; ++mi) {
    #pragma unroll
    for (int j = 0; j < 4; ++j) {
      int grow = mb * 256 + wr * 128 + mi * 16 + l16 * 4 + j;
      #pragma unroll
      for (int h = 0; h < 2; ++h) {
        float v0 = acc[mi][h * 4 + 0][j], v1 = acc[mi][h * 4 + 1][j];
        float v2 = acc[mi][h * 4 + 2][j], v3 = acc[mi][h * 4 + 3][j];
        float mloc = fmaxf(fmaxf(v0, v1), fmaxf(v2, v3));
        #pragma unroll
        for (int d = 1; d < 16; d <<= 1) mloc = fmaxf(mloc, __shfl_xor(mloc, d));
        float sloc = __expf(v0 - mloc) + __expf(v1 - mloc) +
                     __expf(v2 - mloc) + __expf(v3 - mloc);
        #pragma unroll
        for (int d = 1; d < 16; d <<= 1) sloc += __shfl_xor(sloc, d);
        if (l15 == 0)
          part[(size_t)grow * NCHUNK + chunk0 + h] = make_float2(mloc, sloc);
      }
    }
  }
}

// ---------------- per-row merge of partials -> nll[row] ----------------
__device__ __forceinline__ void merge_ms(float& m, float& s, float m2, float s2) {
  if (m2 > m) { s = s * __expf(m - m2) + s2; m = m2; }
  else        { s += s2 * __expf(m2 - m); }
}

__global__ void lse_reduce(const float2* __restrict__ part, const float* __restrict__ tgt,
                           const int* __restrict__ targets, float* __restrict__ nll) {
  int row = blockIdx.x;
  const float2* p = part + (size_t)row * NCHUNK;
  float m = -INFINITY, s = 0.f;
  for (int c = threadIdx.x; c < NCHUNK; c += blockDim.x) {
    float2 v = p[c];
    merge_ms(m, s, v.x, v.y);
  }
  #pragma unroll
  for (int d = 1; d < 64; d <<= 1) {
    float m2 = __shfl_xor(m, d), s2 = __shfl_xor(s, d);
    merge_ms(m, s, m2, s2);
  }
  __shared__ float sm[4], ss[4];
  int wid = threadIdx.x >> 6, lane = threadIdx.x & 63;
  if (lane == 0) { sm[wid] = m; ss[wid] = s; }
  __syncthreads();
  if (threadIdx.x == 0) {
    #pragma unroll
    for (int w2 = 1; w2 < 4; ++w2) merge_ms(m, s, sm[w2], ss[w2]);
    int t = targets[row];
    float out = 0.f;
    if (t != IGNORE_INDEX) out = m + logf(s) - tgt[row];
    nll[row] = out;
  }
}

// ---------------- final scalar: sum(nll)/count ----------------
__global__ void final_kernel(const float* __restrict__ nll, const int* __restrict__ targets,
                             float* __restrict__ out) {
  float sum = 0.f, cnt = 0.f;
  for (int i = threadIdx.x; i < Mrows; i += 64) {
    sum += nll[i];
    cnt += (targets[i] != IGNORE_INDEX) ? 1.f : 0.f;
  }
  #pragma unroll
  for (int d = 1; d < 64; d <<= 1) {
    sum += __shfl_xor(sum, d);
    cnt += __shfl_xor(cnt, d);
  }
  if (threadIdx.x == 0)
    out[0] = (cnt == 0.f) ? sum : sum / fmaxf(cnt, 1.f);
}

extern "C" void kernel_launch(void* const* d_in, const int* in_sizes, int n_in,
                              void* d_out, int out_size, void* d_ws, size_t ws_size,
                              hipStream_t stream) {
  const float* hidden = (const float*)d_in[0];   // [2,1024,1024] f32
  const float* weight = (const float*)d_in[1];   // [128000,1024] f32
  const int* targets  = (const int*)d_in[2];     // [2,1024] i32
  float* out = (float*)d_out;

  char* ws = (char*)d_ws;
  size_t off = 0;
  ushort* wbf = (ushort*)(ws + off); off += (size_t)Vc * Dc * sizeof(ushort);
  ushort* hbf = (ushort*)(ws + off); off += (size_t)Mrows * Dc * sizeof(ushort);
  float2* part = (float2*)(ws + off); off += (size_t)Mrows * NCHUNK * sizeof(float2);
  float* tgt = (float*)(ws + off); off += Mrows * sizeof(float);
  float* nll = (float*)(ws + off); off += Mrows * sizeof(float);
  (void)ws_size; (void)in_sizes; (void)n_in; (void)out_size;

  cast_f32_bf16<<<2048, 256, 0, stream>>>(weight, wbf, (size_t)Vc * Dc / 4);
  cast_f32_bf16<<<256, 256, 0, stream>>>(hidden, hbf, (size_t)Mrows * Dc / 4);
  tgt_kernel<<<Mrows / 4, 256, 0, stream>>>(hidden, weight, targets, tgt);

  gemm_lse4<<<4000, 256, 0, stream>>>(hbf, wbf, part);  // mb=bid&7 (XCD), nb=bid>>3

  lse_reduce<<<Mrows, 256, 0, stream>>>(part, tgt, targets, nll);
  final_kernel<<<1, 64, 0, stream>>>(nll, targets, out);
}

// Round 10
// 782.211 us; speedup vs baseline: 1.2603x; 1.2603x over previous
//
#include <hip/hip_runtime.h>
#include <hip/hip_bf16.h>
#include <math.h>

#define IGNORE_INDEX (-100)

static constexpr int Dc = 1024, Vc = 128000;
static constexpr int Mrows = 2048;        // B*S
static constexpr int Kdim = 1024;
static constexpr int NT = Kdim / 64;      // 16 K-tiles of BK=64
static constexpr int NCHUNK = Vc / 64;    // 2000 partial chunks per row

typedef __bf16 bf16x8_t __attribute__((ext_vector_type(8)));
typedef float f32x4_t __attribute__((ext_vector_type(4)));

__device__ __forceinline__ ushort f2bf(float f) {
  union { float f; unsigned u; } v; v.f = f;
  unsigned u = v.u;
  unsigned r = (u + 0x7FFFu + ((u >> 16) & 1u)) >> 16;  // round-nearest-even
  return (ushort)r;
}

// ---------------- cast fp32 -> bf16 (vectorized, grid-stride) ----------------
__global__ void cast_f32_bf16(const float* __restrict__ in, ushort* __restrict__ out,
                              size_t n4) {
  size_t i = (size_t)blockIdx.x * blockDim.x + threadIdx.x;
  size_t stride = (size_t)gridDim.x * blockDim.x;
  for (; i < n4; i += stride) {
    float4 v = reinterpret_cast<const float4*>(in)[i];
    ushort4 o;
    o.x = f2bf(v.x); o.y = f2bf(v.y); o.z = f2bf(v.z); o.w = f2bf(v.w);
    reinterpret_cast<ushort4*>(out)[i] = o;
  }
}

// ---------------- target logits: fp32 dot(hidden[r], weight[t[r]]) ----------------
__global__ void tgt_kernel(const float* __restrict__ hidden, const float* __restrict__ weight,
                           const int* __restrict__ targets, float* __restrict__ tgt) {
  int row = blockIdx.x * 4 + (threadIdx.x >> 6);
  int lane = threadIdx.x & 63;
  if (row >= Mrows) return;
  int t = targets[row];
  float sum = 0.f;
  if (t != IGNORE_INDEX) {
    const float* h = hidden + (size_t)row * Kdim;
    const float* wv = weight + (size_t)t * Kdim;
    for (int k = lane * 4; k < Kdim; k += 64 * 4) {
      float4 a = *reinterpret_cast<const float4*>(h + k);
      float4 b = *reinterpret_cast<const float4*>(wv + k);
      sum += a.x * b.x + a.y * b.y + a.z * b.z + a.w * b.w;
    }
  }
  #pragma unroll
  for (int d = 1; d < 64; d <<= 1) sum += __shfl_xor(sum, d);
  if (lane == 0) tgt[row] = sum;
}

// ---------------- 256x256 8-wave quadrant-phase GEMM + fused partial LSE ------
// LDS: 2 dbuf x 4 regions {A0,A1,B0,B1}, region = [128 rows][64 k] bf16 = 16KB,
// 128B rows. Swizzle (R7-proven ZERO conflicts): 16B slot' = slot ^ (row&7),
// linear LDS dest + inverse-swizzled GLOBAL source + swizzled ds_read (rule #21).
// BUG FIXED (R8/R9 NaN): kk=1 fragment address is koff0 ^ 64 (XOR), NOT +64 —
// bit6 of koff0 is set for half the lanes, so +64 read wrong slots/rows and ran
// 48B past the last region (stale LDS -> NaN). R7 used XOR correctly.
// Tile-boundary wait: UNIFORM vmcnt(0) (staging is block-cooperative; per-wave
// counted vmcnt would let a wave cross while loads OTHER waves need are in flight).
__device__ __forceinline__ void stage_region(ushort* region, const ushort* gpanel,
                                             int rowBase, int k0, int tid) {
  #pragma unroll
  for (int ld = 0; ld < 2; ++ld) {
    int c = ld * 512 + tid;            // 16B chunk id 0..1023 (8 chunks/128B row)
    int r = c >> 3, slot = c & 7;
    int ko = ((slot ^ (r & 7)) << 3);  // inverse-swizzled source k-offset (elems)
    const ushort* g = gpanel + (size_t)(rowBase + r) * Kdim + k0 + ko;
    __builtin_amdgcn_global_load_lds(
        (const __attribute__((address_space(1))) void*)g,
        (__attribute__((address_space(3))) void*)(region + c * 8), 16, 0, 0);
  }
}

#define MFMA_BF16(A, B, C) __builtin_amdgcn_mfma_f32_16x16x32_bf16((A), (B), (C), 0, 0, 0)

__global__ __launch_bounds__(512, 2) void gemm_lse8(const ushort* __restrict__ Abf,
                                                    const ushort* __restrict__ Bbf,
                                                    float2* __restrict__ part) {
  __shared__ ushort lds[2][4][8192];   // [dbuf][A0,A1,B0,B1][128*64] = 128KB
  const int tid = threadIdx.x;
  const int wid = tid >> 6, lane = tid & 63;
  const int wr = wid >> 2, wc = wid & 3;        // 2M x 4N wave grid
  const int l15 = lane & 15, l16 = lane >> 4;
  const int bid = blockIdx.x;
  const int mb = bid & 7;              // bid%8 = XCD -> each XCD owns one A panel
  const int nb = bid >> 3;             // 0..499; all XCDs stream same B panel

  // swizzled read offset: slot = (kk*4 + l16) ^ (l15&7); kk=1 -> byte offset ^ 64
  const int koff0 = ((l16 ^ (l15 & 7)) << 4);      // bytes
  const int aBase = l15 * 128 + koff0;             // + mi*2048 per frag
  const int bBase = ((wc & 1) * 64 + l15) * 128 + koff0;  // + ni*2048 per frag

  const ushort* gA = Abf + (size_t)(mb * 256) * Kdim;
  const ushort* gB = Bbf + (size_t)(nb * 256) * Kdim;

  f32x4_t acc[8][4];
  #pragma unroll
  for (int i = 0; i < 8; ++i)
    #pragma unroll
    for (int j = 0; j < 4; ++j)
      acc[i][j] = (f32x4_t){0.f, 0.f, 0.f, 0.f};

  // prologue: stage all 4 regions of tile 0
  stage_region(lds[0][0], gA, 0, 0, tid);
  stage_region(lds[0][2], gB, 0, 0, tid);
  stage_region(lds[0][1], gA, 128, 0, tid);
  stage_region(lds[0][3], gB, 128, 0, tid);
  asm volatile("s_waitcnt vmcnt(0)" ::: "memory");
  __builtin_amdgcn_s_barrier();

  for (int t = 0; t < NT; ++t) {
    const int buf = t & 1, nbf = buf ^ 1;
    const char* Ar = (const char*)lds[buf][wr];
    const char* Br = (const char*)lds[buf][2 + (wc >> 1)];
    const bool more = (t + 1 < NT);
    const int k1 = (t + 1) * 64;
    bf16x8_t a[8], b[8];

    // ---- ph1: read A(mi0-3) + B(ni0-1); stage A0' + B0'; MFMA Q00 ----
    #pragma unroll
    for (int mi = 0; mi < 4; ++mi) {
      const int aOff = aBase + mi * 2048;
      a[mi * 2 + 0] = *reinterpret_cast<const bf16x8_t*>(Ar + aOff);
      a[mi * 2 + 1] = *reinterpret_cast<const bf16x8_t*>(Ar + (aOff ^ 64));
    }
    #pragma unroll
    for (int ni = 0; ni < 2; ++ni) {
      const int bOff = bBase + ni * 2048;
      b[ni * 2 + 0] = *reinterpret_cast<const bf16x8_t*>(Br + bOff);
      b[ni * 2 + 1] = *reinterpret_cast<const bf16x8_t*>(Br + (bOff ^ 64));
    }
    if (more) {
      stage_region(lds[nbf][0], gA, 0, k1, tid);
      stage_region(lds[nbf][2], gB, 0, k1, tid);
    }
    __builtin_amdgcn_s_barrier();
    __builtin_amdgcn_s_setprio(1);
    #pragma unroll
    for (int mi = 0; mi < 4; ++mi) {
      acc[mi][0] = MFMA_BF16(a[mi * 2 + 0], b[0], acc[mi][0]);
      acc[mi][0] = MFMA_BF16(a[mi * 2 + 1], b[1], acc[mi][0]);
      acc[mi][1] = MFMA_BF16(a[mi * 2 + 0], b[2], acc[mi][1]);
      acc[mi][1] = MFMA_BF16(a[mi * 2 + 1], b[3], acc[mi][1]);
    }
    __builtin_amdgcn_s_setprio(0);
    __builtin_amdgcn_s_barrier();

    // ---- ph2: read B(ni2-3); stage A1' + B1'; MFMA Q01 ----
    #pragma unroll
    for (int ni = 2; ni < 4; ++ni) {
      const int bOff = bBase + ni * 2048;
      b[ni * 2 + 0] = *reinterpret_cast<const bf16x8_t*>(Br + bOff);
      b[ni * 2 + 1] = *reinterpret_cast<const bf16x8_t*>(Br + (bOff ^ 64));
    }
    if (more) {
      stage_region(lds[nbf][1], gA, 128, k1, tid);
      stage_region(lds[nbf][3], gB, 128, k1, tid);
    }
    __builtin_amdgcn_s_barrier();
    __builtin_amdgcn_s_setprio(1);
    #pragma unroll
    for (int mi = 0; mi < 4; ++mi) {
      acc[mi][2] = MFMA_BF16(a[mi * 2 + 0], b[4], acc[mi][2]);
      acc[mi][2] = MFMA_BF16(a[mi * 2 + 1], b[5], acc[mi][2]);
      acc[mi][3] = MFMA_BF16(a[mi * 2 + 0], b[6], acc[mi][3]);
      acc[mi][3] = MFMA_BF16(a[mi * 2 + 1], b[7], acc[mi][3]);
    }
    __builtin_amdgcn_s_setprio(0);
    __builtin_amdgcn_s_barrier();

    // ---- ph3: read A(mi4-7); MFMA Q10 ----
    #pragma unroll
    for (int mi = 4; mi < 8; ++mi) {
      const int aOff = aBase + mi * 2048;
      a[(mi - 4) * 2 + 0] = *reinterpret_cast<const bf16x8_t*>(Ar + aOff);
      a[(mi - 4) * 2 + 1] = *reinterpret_cast<const bf16x8_t*>(Ar + (aOff ^ 64));
    }
    __builtin_amdgcn_s_barrier();
    __builtin_amdgcn_s_setprio(1);
    #pragma unroll
    for (int mi = 0; mi < 4; ++mi) {
      acc[mi + 4][0] = MFMA_BF16(a[mi * 2 + 0], b[0], acc[mi + 4][0]);
      acc[mi + 4][0] = MFMA_BF16(a[mi * 2 + 1], b[1], acc[mi + 4][0]);
      acc[mi + 4][1] = MFMA_BF16(a[mi * 2 + 0], b[2], acc[mi + 4][1]);
      acc[mi + 4][1] = MFMA_BF16(a[mi * 2 + 1], b[3], acc[mi + 4][1]);
    }
    __builtin_amdgcn_s_setprio(0);
    __builtin_amdgcn_s_barrier();

    // ---- ph4: MFMA Q11; UNIFORM drain before tile boundary (race-safe) ----
    __builtin_amdgcn_s_setprio(1);
    #pragma unroll
    for (int mi = 0; mi < 4; ++mi) {
      acc[mi + 4][2] = MFMA_BF16(a[mi * 2 + 0], b[4], acc[mi + 4][2]);
      acc[mi + 4][2] = MFMA_BF16(a[mi * 2 + 1], b[5], acc[mi + 4][2]);
      acc[mi + 4][3] = MFMA_BF16(a[mi * 2 + 0], b[6], acc[mi + 4][3]);
      acc[mi + 4][3] = MFMA_BF16(a[mi * 2 + 1], b[7], acc[mi + 4][3]);
    }
    __builtin_amdgcn_s_setprio(0);
    if (more) {
      asm volatile("s_waitcnt vmcnt(0)" ::: "memory");
      __builtin_amdgcn_s_barrier();
    }
  }

  // fused partial-LSE epilogue. acc[mi][ni][j]: row = wr*128+mi*16+l16*4+j,
  // col = wc*64+ni*16+l15 (m89-verified C/D layout)
  const int chunk = nb * 4 + wc;
  #pragma unroll
  for (int mi = 0; mi < 8; ++mi) {
    #pragma unroll
    for (int j = 0; j < 4; ++j) {
      float v0 = acc[mi][0][j], v1 = acc[mi][1][j], v2 = acc[mi][2][j], v3 = acc[mi][3][j];
      float mloc = fmaxf(fmaxf(v0, v1), fmaxf(v2, v3));
      #pragma unroll
      for (int d = 1; d < 16; d <<= 1) mloc = fmaxf(mloc, __shfl_xor(mloc, d));
      float sloc = __expf(v0 - mloc) + __expf(v1 - mloc) +
                   __expf(v2 - mloc) + __expf(v3 - mloc);
      #pragma unroll
      for (int d = 1; d < 16; d <<= 1) sloc += __shfl_xor(sloc, d);
      if (l15 == 0) {
        int grow = mb * 256 + wr * 128 + mi * 16 + l16 * 4 + j;
        part[(size_t)grow * NCHUNK + chunk] = make_float2(mloc, sloc);
      }
    }
  }
}

// ---------------- per-row merge of partials -> nll[row] ----------------
__device__ __forceinline__ void merge_ms(float& m, float& s, float m2, float s2) {
  if (m2 > m) { s = s * __expf(m - m2) + s2; m = m2; }
  else        { s += s2 * __expf(m2 - m); }
}

__global__ void lse_reduce(const float2* __restrict__ part, const float* __restrict__ tgt,
                           const int* __restrict__ targets, float* __restrict__ nll) {
  int row = blockIdx.x;
  const float2* p = part + (size_t)row * NCHUNK;
  float m = -INFINITY, s = 0.f;
  for (int c = threadIdx.x; c < NCHUNK; c += blockDim.x) {
    float2 v = p[c];
    merge_ms(m, s, v.x, v.y);
  }
  #pragma unroll
  for (int d = 1; d < 64; d <<= 1) {
    float m2 = __shfl_xor(m, d), s2 = __shfl_xor(s, d);
    merge_ms(m, s, m2, s2);
  }
  __shared__ float sm[4], ss[4];
  int wid = threadIdx.x >> 6, lane = threadIdx.x & 63;
  if (lane == 0) { sm[wid] = m; ss[wid] = s; }
  __syncthreads();
  if (threadIdx.x == 0) {
    #pragma unroll
    for (int w2 = 1; w2 < 4; ++w2) merge_ms(m, s, sm[w2], ss[w2]);
    int t = targets[row];
    float out = 0.f;
    if (t != IGNORE_INDEX) out = m + logf(s) - tgt[row];
    nll[row] = out;
  }
}

// ---------------- final scalar: sum(nll)/count ----------------
__global__ void final_kernel(const float* __restrict__ nll, const int* __restrict__ targets,
                             float* __restrict__ out) {
  float sum = 0.f, cnt = 0.f;
  for (int i = threadIdx.x; i < Mrows; i += 64) {
    sum += nll[i];
    cnt += (targets[i] != IGNORE_INDEX) ? 1.f : 0.f;
  }
  #pragma unroll
  for (int d = 1; d < 64; d <<= 1) {
    sum += __shfl_xor(sum, d);
    cnt += __shfl_xor(cnt, d);
  }
  if (threadIdx.x == 0)
    out[0] = (cnt == 0.f) ? sum : sum / fmaxf(cnt, 1.f);
}

extern "C" void kernel_launch(void* const* d_in, const int* in_sizes, int n_in,
                              void* d_out, int out_size, void* d_ws, size_t ws_size,
                              hipStream_t stream) {
  const float* hidden = (const float*)d_in[0];   // [2,1024,1024] f32
  const float* weight = (const float*)d_in[1];   // [128000,1024] f32
  const int* targets  = (const int*)d_in[2];     // [2,1024] i32
  float* out = (float*)d_out;

  char* ws = (char*)d_ws;
  size_t off = 0;
  ushort* wbf = (ushort*)(ws + off); off += (size_t)Vc * Dc * sizeof(ushort);
  ushort* hbf = (ushort*)(ws + off); off += (size_t)Mrows * Dc * sizeof(ushort);
  float2* part = (float2*)(ws + off); off += (size_t)Mrows * NCHUNK * sizeof(float2);
  float* tgt = (float*)(ws + off); off += Mrows * sizeof(float);
  float* nll = (float*)(ws + off); off += Mrows * sizeof(float);
  (void)ws_size; (void)in_sizes; (void)n_in; (void)out_size;

  cast_f32_bf16<<<2048, 256, 0, stream>>>(weight, wbf, (size_t)Vc * Dc / 4);
  cast_f32_bf16<<<256, 256, 0, stream>>>(hidden, hbf, (size_t)Mrows * Dc / 4);
  tgt_kernel<<<Mrows / 4, 256, 0, stream>>>(hidden, weight, targets, tgt);

  gemm_lse8<<<4000, 512, 0, stream>>>(hbf, wbf, part);  // mb=bid&7 (XCD), nb=bid>>3

  lse_reduce<<<Mrows, 256, 0, stream>>>(part, tgt, targets, nll);
  final_kernel<<<1, 64, 0, stream>>>(nll, targets, out);
}

// Round 11
// 779.965 us; speedup vs baseline: 1.2639x; 1.0029x over previous
//
#include <hip/hip_runtime.h>
#include <hip/hip_bf16.h>
#include <math.h>

#define IGNORE_INDEX (-100)

static constexpr int Dc = 1024, Vc = 128000;
static constexpr int Mrows = 2048;        // B*S
static constexpr int Kdim = 1024;
static constexpr int BK = 32;
static constexpr int NT = Kdim / BK;      // 32 K-tiles of BK=32
static constexpr int NCHUNK = Vc / 64;    // 2000 partial chunks per row

typedef __bf16 bf16x8_t __attribute__((ext_vector_type(8)));
typedef float f32x4_t __attribute__((ext_vector_type(4)));

__device__ __forceinline__ ushort f2bf(float f) {
  union { float f; unsigned u; } v; v.f = f;
  unsigned u = v.u;
  unsigned r = (u + 0x7FFFu + ((u >> 16) & 1u)) >> 16;  // round-nearest-even
  return (ushort)r;
}

// ---------------- cast fp32 -> bf16 (vectorized, grid-stride) ----------------
__global__ void cast_f32_bf16(const float* __restrict__ in, ushort* __restrict__ out,
                              size_t n4) {
  size_t i = (size_t)blockIdx.x * blockDim.x + threadIdx.x;
  size_t stride = (size_t)gridDim.x * blockDim.x;
  for (; i < n4; i += stride) {
    float4 v = reinterpret_cast<const float4*>(in)[i];
    ushort4 o;
    o.x = f2bf(v.x); o.y = f2bf(v.y); o.z = f2bf(v.z); o.w = f2bf(v.w);
    reinterpret_cast<ushort4*>(out)[i] = o;
  }
}

// ---------------- target logits: fp32 dot(hidden[r], weight[t[r]]) ----------------
__global__ void tgt_kernel(const float* __restrict__ hidden, const float* __restrict__ weight,
                           const int* __restrict__ targets, float* __restrict__ tgt) {
  int row = blockIdx.x * 4 + (threadIdx.x >> 6);
  int lane = threadIdx.x & 63;
  if (row >= Mrows) return;
  int t = targets[row];
  float sum = 0.f;
  if (t != IGNORE_INDEX) {
    const float* h = hidden + (size_t)row * Kdim;
    const float* wv = weight + (size_t)t * Kdim;
    for (int k = lane * 4; k < Kdim; k += 64 * 4) {
      float4 a = *reinterpret_cast<const float4*>(h + k);
      float4 b = *reinterpret_cast<const float4*>(wv + k);
      sum += a.x * b.x + a.y * b.y + a.z * b.z + a.w * b.w;
    }
  }
  #pragma unroll
  for (int d = 1; d < 64; d <<= 1) sum += __shfl_xor(sum, d);
  if (lane == 0) tgt[row] = sum;
}

// ---------------- 256x256 8-wave RING-pipelined GEMM + fused partial LSE ------
// LDS: 3-deep ring x 4 regions {A0,A1,B0,B1}, region = [128 rows][32 k] = 8KB,
// 64B rows -> 96KB total. Per tile: stage t+2 (4 loads/thread) + 12 ds_read_b128
// + 32 MFMA in ONE basic block (compiler interleaves), then counted vmcnt(4)
// (retires t+1's loads, issued 2 tiles earlier; t+2's 4 ride across) + 1 barrier.
// Safety: vmcnt retirement is in-order; count uniform across waves; each wave's
// barrier arrival certifies its own t+1 loads retired (R8 lesson upheld).
// Swizzle (octet model, R6 residual explained): 16B slot' = slot ^ ((row>>1)&3)
// -> every lane-octet of a wave b128 hits 8 distinct 16B bank groups. Applied as
// linear LDS dest + inverse-swizzled GLOBAL source + swizzled ds_read (rule #21).
#define MFMA_BF16(A, B, C) __builtin_amdgcn_mfma_f32_16x16x32_bf16((A), (B), (C), 0, 0, 0)
#define GLDS(g, l) __builtin_amdgcn_global_load_lds( \
    (const __attribute__((address_space(1))) void*)(g), \
    (__attribute__((address_space(3))) void*)(l), 16, 0, 0)

__global__ __launch_bounds__(512, 2) void gemm_lse_ring(const ushort* __restrict__ Abf,
                                                        const ushort* __restrict__ Bbf,
                                                        float2* __restrict__ part) {
  __shared__ ushort lds[3][4][4096];   // [ring][A0,A1,B0,B1][128*32] = 96KB
  const int tid = threadIdx.x;
  const int wid = tid >> 6, lane = tid & 63;
  const int wr = wid >> 2, wc = wid & 3;        // 2M x 4N wave grid
  const int l15 = lane & 15, l16 = lane >> 4;
  const int bid = blockIdx.x;
  const int mb = bid & 7;              // bid%8 = XCD -> each XCD owns one A panel
  const int nb = bid >> 3;             // 0..499; all XCDs stream same B panel

  // stage-side: thread tid owns chunk c=tid of each region (1 load/region)
  const int sr = tid >> 2, sslot = tid & 3;
  const int sko = ((sslot ^ ((sr >> 1) & 3)) << 3);   // inverse-swizzled src k (elems)
  const ushort* gA = Abf + (size_t)(mb * 256) * Kdim;
  const ushort* gB = Bbf + (size_t)(nb * 256) * Kdim;
  const ushort* sg0 = gA + (size_t)sr * Kdim + sko;          // A rows 0-127
  const ushort* sg1 = gA + (size_t)(128 + sr) * Kdim + sko;  // A rows 128-255
  const ushort* sg2 = gB + (size_t)sr * Kdim + sko;          // B rows 0-127
  const ushort* sg3 = gB + (size_t)(128 + sr) * Kdim + sko;  // B rows 128-255

  // read-side swizzled offsets: row stride 64B; slot' = l16 ^ ((row>>1)&3),
  // frag bases are multiples of 16 rows so (row>>1)&3 = (l15>>1)&3 per lane.
  const int koff = ((l16 ^ ((l15 >> 1) & 3)) << 4);   // bytes
  const int aBase = l15 * 64 + koff;                  // + mi*1024 per frag
  const int bBase = ((wc & 1) * 64 + l15) * 64 + koff; // + ni*1024 per frag

  f32x4_t acc[8][4];
  #pragma unroll
  for (int i = 0; i < 8; ++i)
    #pragma unroll
    for (int j = 0; j < 4; ++j)
      acc[i][j] = (f32x4_t){0.f, 0.f, 0.f, 0.f};

  #define STAGE(ridx, k0) do { \
    GLDS(sg0 + (k0), &lds[ridx][0][tid * 8]); \
    GLDS(sg1 + (k0), &lds[ridx][1][tid * 8]); \
    GLDS(sg2 + (k0), &lds[ridx][2][tid * 8]); \
    GLDS(sg3 + (k0), &lds[ridx][3][tid * 8]); \
  } while (0)

  // prologue: tiles 0,1 staged; wait tile0 (vmcnt(4) leaves tile1's 4 in flight)
  STAGE(0, 0);
  STAGE(1, BK);
  asm volatile("s_waitcnt vmcnt(4)" ::: "memory");
  __builtin_amdgcn_s_barrier();

  int cur = 0;
  for (int t = 0; t < NT; ++t) {
    if (t + 2 < NT) {
      int stg = cur + 2; if (stg >= 3) stg -= 3;
      STAGE(stg, (t + 2) * BK);
    }
    const char* Ar = (const char*)lds[cur][wr];
    const char* Br = (const char*)lds[cur][2 + (wc >> 1)];
    bf16x8_t a[8], b[4];
    #pragma unroll
    for (int mi = 0; mi < 8; ++mi)
      a[mi] = *reinterpret_cast<const bf16x8_t*>(Ar + aBase + mi * 1024);
    #pragma unroll
    for (int ni = 0; ni < 4; ++ni)
      b[ni] = *reinterpret_cast<const bf16x8_t*>(Br + bBase + ni * 1024);
    __builtin_amdgcn_s_setprio(1);
    #pragma unroll
    for (int mi = 0; mi < 8; ++mi)
      #pragma unroll
      for (int ni = 0; ni < 4; ++ni)
        acc[mi][ni] = MFMA_BF16(a[mi], b[ni], acc[mi][ni]);
    __builtin_amdgcn_s_setprio(0);
    if (t + 2 < NT) {
      asm volatile("s_waitcnt vmcnt(4)" ::: "memory");  // t+1's retired; t+2's ride
      __builtin_amdgcn_s_barrier();
    } else if (t + 1 < NT) {
      asm volatile("s_waitcnt vmcnt(0)" ::: "memory");  // last-tile loads (old) done
      __builtin_amdgcn_s_barrier();
    }
    cur = cur + 1; if (cur >= 3) cur = 0;
  }
  #undef STAGE

  // fused partial-LSE epilogue. acc[mi][ni][j]: row = wr*128+mi*16+l16*4+j,
  // col = wc*64+ni*16+l15 (m89-verified C/D layout)
  const int chunk = nb * 4 + wc;
  #pragma unroll
  for (int mi = 0; mi < 8; ++mi) {
    #pragma unroll
    for (int j = 0; j < 4; ++j) {
      float v0 = acc[mi][0][j], v1 = acc[mi][1][j], v2 = acc[mi][2][j], v3 = acc[mi][3][j];
      float mloc = fmaxf(fmaxf(v0, v1), fmaxf(v2, v3));
      #pragma unroll
      for (int d = 1; d < 16; d <<= 1) mloc = fmaxf(mloc, __shfl_xor(mloc, d));
      float sloc = __expf(v0 - mloc) + __expf(v1 - mloc) +
                   __expf(v2 - mloc) + __expf(v3 - mloc);
      #pragma unroll
      for (int d = 1; d < 16; d <<= 1) sloc += __shfl_xor(sloc, d);
      if (l15 == 0) {
        int grow = mb * 256 + wr * 128 + mi * 16 + l16 * 4 + j;
        part[(size_t)grow * NCHUNK + chunk] = make_float2(mloc, sloc);
      }
    }
  }
}

// ---------------- per-row merge of partials -> nll[row] ----------------
__device__ __forceinline__ void merge_ms(float& m, float& s, float m2, float s2) {
  if (m2 > m) { s = s * __expf(m - m2) + s2; m = m2; }
  else        { s += s2 * __expf(m2 - m); }
}

__global__ void lse_reduce(const float2* __restrict__ part, const float* __restrict__ tgt,
                           const int* __restrict__ targets, float* __restrict__ nll) {
  int row = blockIdx.x;
  const float2* p = part + (size_t)row * NCHUNK;
  float m = -INFINITY, s = 0.f;
  for (int c = threadIdx.x; c < NCHUNK; c += blockDim.x) {
    float2 v = p[c];
    merge_ms(m, s, v.x, v.y);
  }
  #pragma unroll
  for (int d = 1; d < 64; d <<= 1) {
    float m2 = __shfl_xor(m, d), s2 = __shfl_xor(s, d);
    merge_ms(m, s, m2, s2);
  }
  __shared__ float sm[4], ss[4];
  int wid = threadIdx.x >> 6, lane = threadIdx.x & 63;
  if (lane == 0) { sm[wid] = m; ss[wid] = s; }
  __syncthreads();
  if (threadIdx.x == 0) {
    #pragma unroll
    for (int w2 = 1; w2 < 4; ++w2) merge_ms(m, s, sm[w2], ss[w2]);
    int t = targets[row];
    float out = 0.f;
    if (t != IGNORE_INDEX) out = m + logf(s) - tgt[row];
    nll[row] = out;
  }
}

// ---------------- final scalar: sum(nll)/count ----------------
__global__ void final_kernel(const float* __restrict__ nll, const int* __restrict__ targets,
                             float* __restrict__ out) {
  float sum = 0.f, cnt = 0.f;
  for (int i = threadIdx.x; i < Mrows; i += 64) {
    sum += nll[i];
    cnt += (targets[i] != IGNORE_INDEX) ? 1.f : 0.f;
  }
  #pragma unroll
  for (int d = 1; d < 64; d <<= 1) {
    sum += __shfl_xor(sum, d);
    cnt += __shfl_xor(cnt, d);
  }
  if (threadIdx.x == 0)
    out[0] = (cnt == 0.f) ? sum : sum / fmaxf(cnt, 1.f);
}

extern "C" void kernel_launch(void* const* d_in, const int* in_sizes, int n_in,
                              void* d_out, int out_size, void* d_ws, size_t ws_size,
                              hipStream_t stream) {
  const float* hidden = (const float*)d_in[0];   // [2,1024,1024] f32
  const float* weight = (const float*)d_in[1];   // [128000,1024] f32
  const int* targets  = (const int*)d_in[2];     // [2,1024] i32
  float* out = (float*)d_out;

  char* ws = (char*)d_ws;
  size_t off = 0;
  ushort* wbf = (ushort*)(ws + off); off += (size_t)Vc * Dc * sizeof(ushort);
  ushort* hbf = (ushort*)(ws + off); off += (size_t)Mrows * Dc * sizeof(ushort);
  float2* part = (float2*)(ws + off); off += (size_t)Mrows * NCHUNK * sizeof(float2);
  float* tgt = (float*)(ws + off); off += Mrows * sizeof(float);
  float* nll = (float*)(ws + off); off += Mrows * sizeof(float);
  (void)ws_size; (void)in_sizes; (void)n_in; (void)out_size;

  cast_f32_bf16<<<2048, 256, 0, stream>>>(weight, wbf, (size_t)Vc * Dc / 4);
  cast_f32_bf16<<<256, 256, 0, stream>>>(hidden, hbf, (size_t)Mrows * Dc / 4);
  tgt_kernel<<<Mrows / 4, 256, 0, stream>>>(hidden, weight, targets, tgt);

  gemm_lse_ring<<<4000, 512, 0, stream>>>(hbf, wbf, part);  // mb=bid&7 (XCD), nb=bid>>3

  lse_reduce<<<Mrows, 256, 0, stream>>>(part, tgt, targets, nll);
  final_kernel<<<1, 64, 0, stream>>>(nll, targets, out);
}